// Round 1
// 593.249 us; speedup vs baseline: 1.3680x; 1.3680x over previous
//
#include <hip/hip_runtime.h>
#include <cstdint>
#include <cstddef>

typedef __bf16 bf16;
typedef __bf16 bf16x8 __attribute__((ext_vector_type(8)));
typedef float f32x4 __attribute__((ext_vector_type(4)));

// Problem: B=8, L=1024, S=1000 (pad 1024), GRAPH=512, LLM=4096, H=8, E=128, DKH=1024
// Inputs fp32. OUTPUT fp32.

__device__ __forceinline__ void gload_lds16(const void* g, void* l) {
    typedef __attribute__((address_space(1))) void gv;
    typedef __attribute__((address_space(3))) void lv;
    __builtin_amdgcn_global_load_lds((gv*)g, (lv*)l, 16, 0, 0);
}

// ---------------------------------------------------------------------------
// Flat fp32 -> bf16 cast; elements >= n_in written as 0 (row padding).
// ---------------------------------------------------------------------------
__global__ __launch_bounds__(256) void cast_f32_bf16(
    const float* __restrict__ in, bf16* __restrict__ out, size_t n_in)
{
    const size_t i = ((size_t)blockIdx.x * 256 + threadIdx.x) * 8;
    f32x4 a = (f32x4){0.f, 0.f, 0.f, 0.f};
    f32x4 b = (f32x4){0.f, 0.f, 0.f, 0.f};
    if (i < n_in) {
        a = *(const f32x4*)(in + i);
        b = *(const f32x4*)(in + i + 4);
    }
    bf16x8 o;
    o[0] = (bf16)a[0]; o[1] = (bf16)a[1]; o[2] = (bf16)a[2]; o[3] = (bf16)a[3];
    o[4] = (bf16)b[0]; o[5] = (bf16)b[1]; o[6] = (bf16)b[2]; o[7] = (bf16)b[3];
    *(bf16x8*)(out + i) = o;
}

// ---------------------------------------------------------------------------
// Transpose + cast: in fp32 [R,C] -> out bf16 [C,R]. R,C multiples of 32.
// ---------------------------------------------------------------------------
__global__ __launch_bounds__(256) void transpose_cast(
    const float* __restrict__ in, bf16* __restrict__ out, int R, int C)
{
    __shared__ bf16 tile[32][33];
    const int tx = threadIdx.x & 31, ty = threadIdx.x >> 5;
    const int c0 = blockIdx.x * 32, r0 = blockIdx.y * 32;
    #pragma unroll
    for (int i = ty; i < 32; i += 8)
        tile[i][tx] = (bf16)in[(size_t)(r0 + i) * C + (c0 + tx)];
    __syncthreads();
    #pragma unroll
    for (int i = ty; i < 32; i += 8)
        out[(size_t)(c0 + i) * R + (r0 + tx)] = tile[tx][i];
}

// ---------------------------------------------------------------------------
// GEMM: C[M,N] = A[M,K] @ Bt[N,K]^T + bias[N]; A,Bt bf16, bias fp32, fp32 acc.
// 256 thr = 4 waves; 128x128 C-tile; 2x2 waves of 64x64 (4x4 MFMA 16x16x32).
// transC: store C[n*ldc+m]. outF32: store fp32 (else bf16).
// ---------------------------------------------------------------------------
__global__ __launch_bounds__(256) void gemm_bt(
    const bf16* __restrict__ A, const bf16* __restrict__ Bt,
    const float* __restrict__ bias, void* __restrict__ Cv,
    int M, int N, int K, int lda, int ldb, int ldc, int transC, int outF32)
{
    __shared__ __align__(16) bf16 As[128 * 32];
    __shared__ __align__(16) bf16 Bs[128 * 32];

    const int tid = threadIdx.x;
    const int w = tid >> 6, ln = tid & 63;
    const int bm = blockIdx.y, bn = blockIdx.x;
    const int wm = (w >> 1) * 64, wn = (w & 1) * 64;
    const int rgrp = ln >> 4, cl = ln & 15;

    f32x4 acc[4][4];
    #pragma unroll
    for (int mt = 0; mt < 4; ++mt)
        #pragma unroll
        for (int nt = 0; nt < 4; ++nt)
            acc[mt][nt] = (f32x4){0.f, 0.f, 0.f, 0.f};

    for (int k0 = 0; k0 < K; k0 += 32) {
        #pragma unroll
        for (int j = 0; j < 2; ++j) {
            const int t2 = tid + 256 * j;
            int arow = bm * 128 + (t2 >> 2);
            if (arow > M - 1) arow = M - 1;
            const bf16* ag = A + (size_t)arow * lda + k0 + (t2 & 3) * 8;
            gload_lds16(ag, (char*)As + j * 4096 + w * 1024);
            const int brow = bn * 128 + (t2 >> 2);
            const bf16* bg = Bt + (size_t)brow * ldb + k0 + (t2 & 3) * 8;
            gload_lds16(bg, (char*)Bs + j * 4096 + w * 1024);
        }
        __syncthreads();

        bf16x8 af[4], bfr[4];
        #pragma unroll
        for (int mt = 0; mt < 4; ++mt)
            af[mt] = *(const bf16x8*)(As + (wm + mt * 16 + cl) * 32 + rgrp * 8);
        #pragma unroll
        for (int nt = 0; nt < 4; ++nt)
            bfr[nt] = *(const bf16x8*)(Bs + (wn + nt * 16 + cl) * 32 + rgrp * 8);
        #pragma unroll
        for (int mt = 0; mt < 4; ++mt)
            #pragma unroll
            for (int nt = 0; nt < 4; ++nt)
                acc[mt][nt] = __builtin_amdgcn_mfma_f32_16x16x32_bf16(
                    af[mt], bfr[nt], acc[mt][nt], 0, 0, 0);
        __syncthreads();
    }

    // D layout per 16x16 tile: row = rgrp*4 + reg, col = cl.
    #pragma unroll
    for (int nt = 0; nt < 4; ++nt) {
        const int col = bn * 128 + wn + nt * 16 + cl;
        const float bvv = bias ? bias[col] : 0.f;
        #pragma unroll
        for (int mt = 0; mt < 4; ++mt) {
            #pragma unroll
            for (int reg = 0; reg < 4; ++reg) {
                const int row = bm * 128 + wm + mt * 16 + rgrp * 4 + reg;
                if (row < M) {
                    const float v = acc[mt][nt][reg] + bvv;
                    const size_t idx = transC ? (size_t)col * ldc + row
                                              : (size_t)row * ldc + col;
                    if (outF32) ((float*)Cv)[idx] = v;
                    else        ((bf16*)Cv)[idx] = (bf16)v;
                }
            }
        }
    }
}

// ---------------------------------------------------------------------------
// 64x64-tile GEMM variant (BK=64) for small M,N with big K: 4x more blocks
// than gemm_bt at the same M,N -> fills the chip for the K/V projections
// (M=N=1024 -> 256 blocks vs 64). 4 waves as 2x2 of 32x32 (2x2 MFMA tiles).
// ---------------------------------------------------------------------------
__global__ __launch_bounds__(256) void gemm_bt64(
    const bf16* __restrict__ A, const bf16* __restrict__ Bt,
    const float* __restrict__ bias, void* __restrict__ Cv,
    int M, int N, int K, int lda, int ldb, int ldc, int transC, int outF32)
{
    __shared__ __align__(16) bf16 As[64 * 64];
    __shared__ __align__(16) bf16 Bs[64 * 64];

    const int tid = threadIdx.x;
    const int w = tid >> 6, ln = tid & 63;
    const int bm = blockIdx.y, bn = blockIdx.x;
    const int wm = (w >> 1) * 32, wn = (w & 1) * 32;
    const int rgrp = ln >> 4, cl = ln & 15;

    f32x4 acc[2][2];
    #pragma unroll
    for (int mt = 0; mt < 2; ++mt)
        #pragma unroll
        for (int nt = 0; nt < 2; ++nt)
            acc[mt][nt] = (f32x4){0.f, 0.f, 0.f, 0.f};

    for (int k0 = 0; k0 < K; k0 += 64) {
        // Stage [64 rows][64 k] bf16 = 8 KB per matrix; LDS dest must be
        // linear in lane order: byte(row,k) = row*128 + k*2; lane l of wave w,
        // call j lands at j*4096 + w*1024 + l*16 -> row = j*32+w*8+(l>>3),
        // k = (l&7)*8.
        #pragma unroll
        for (int j = 0; j < 2; ++j) {
            int arow = bm * 64 + j * 32 + w * 8 + (ln >> 3);
            if (arow > M - 1) arow = M - 1;
            const bf16* ag = A + (size_t)arow * lda + k0 + (ln & 7) * 8;
            gload_lds16(ag, (char*)As + j * 4096 + w * 1024);
            int brow = bn * 64 + j * 32 + w * 8 + (ln >> 3);
            if (brow > N - 1) brow = N - 1;
            const bf16* bg = Bt + (size_t)brow * ldb + k0 + (ln & 7) * 8;
            gload_lds16(bg, (char*)Bs + j * 4096 + w * 1024);
        }
        __syncthreads();

        bf16x8 af[2][2], bfr[2][2];
        #pragma unroll
        for (int mt = 0; mt < 2; ++mt)
            #pragma unroll
            for (int kk = 0; kk < 2; ++kk)
                af[mt][kk] = *(const bf16x8*)(As + (wm + mt * 16 + cl) * 64 + kk * 32 + rgrp * 8);
        #pragma unroll
        for (int nt = 0; nt < 2; ++nt)
            #pragma unroll
            for (int kk = 0; kk < 2; ++kk)
                bfr[nt][kk] = *(const bf16x8*)(Bs + (wn + nt * 16 + cl) * 64 + kk * 32 + rgrp * 8);
        #pragma unroll
        for (int mt = 0; mt < 2; ++mt)
            #pragma unroll
            for (int nt = 0; nt < 2; ++nt)
                #pragma unroll
                for (int kk = 0; kk < 2; ++kk)
                    acc[mt][nt] = __builtin_amdgcn_mfma_f32_16x16x32_bf16(
                        af[mt][kk], bfr[nt][kk], acc[mt][nt], 0, 0, 0);
        __syncthreads();
    }

    #pragma unroll
    for (int nt = 0; nt < 2; ++nt) {
        const int col = bn * 64 + wn + nt * 16 + cl;
        const float bvv = bias ? bias[col] : 0.f;
        #pragma unroll
        for (int mt = 0; mt < 2; ++mt) {
            #pragma unroll
            for (int reg = 0; reg < 4; ++reg) {
                const int row = bm * 64 + wm + mt * 16 + rgrp * 4 + reg;
                if (row < M) {
                    const float v = acc[mt][nt][reg] + bvv;
                    const size_t idx = transC ? (size_t)col * ldc + row
                                              : (size_t)row * ldc + col;
                    if (outF32) ((float*)Cv)[idx] = v;
                    else        ((bf16*)Cv)[idx] = (bf16)v;
                }
            }
        }
    }
}

// ---------------------------------------------------------------------------
// Flash attention v2: Q [8192,1024] (col=h*128+e), Kb [1024,1024] (row=s),
// Vt [1024,1024] = V^T (row=e, col=s), O [8192,1024] bf16.
// 256 thr = 4 waves; wave = 32 Q rows (2x16); grid (B*H=64, L/128=8).
// s-tiles of 32. NO __syncthreads: P tile is wave-private (same-wave LDS
// write->read ordering via compiler lgkmcnt). V frags issued before softmax
// so their L2 latency hides under the shuffle-reduce chain.
// ---------------------------------------------------------------------------
__global__ __launch_bounds__(256, 2) void flash_attn(
    const bf16* __restrict__ Q, const bf16* __restrict__ Kb,
    const bf16* __restrict__ Vt, bf16* __restrict__ O)
{
    const int tid = threadIdx.x;
    const int w = tid >> 6, ln = tid & 63;
    const int b = blockIdx.x >> 3, h = blockIdx.x & 7;
    const int l0 = blockIdx.y * 128 + w * 32;
    const int grp = ln >> 4, cl = ln & 15;
    // scale * log2(e): softmax computed in exp2 domain (one mul + v_exp_f32).
    const float sl2 = 0.08838834764831845f * 1.44269504088896340736f;

    __shared__ __align__(16) bf16 Pl[4][2][16 * 40];  // per-wave P tiles, stride 40

    bf16x8 qf[2][4];
    #pragma unroll
    for (int m = 0; m < 2; ++m) {
        const bf16* qp = Q + (size_t)(b * 1024 + l0 + m * 16 + cl) * 1024 + h * 128 + grp * 8;
        #pragma unroll
        for (int kk = 0; kk < 4; ++kk) qf[m][kk] = *(const bf16x8*)(qp + kk * 32);
    }

    f32x4 o[2][8];
    #pragma unroll
    for (int m = 0; m < 2; ++m)
        #pragma unroll
        for (int nt = 0; nt < 8; ++nt) o[m][nt] = (f32x4){0.f, 0.f, 0.f, 0.f};
    float m_[2][4] = {{-1e30f, -1e30f, -1e30f, -1e30f}, {-1e30f, -1e30f, -1e30f, -1e30f}};
    float l_[2][4] = {{0.f, 0.f, 0.f, 0.f}, {0.f, 0.f, 0.f, 0.f}};

    for (int s0 = 0; s0 < 1024; s0 += 32) {
        // K frags (8 x 16B loads, shared by both row-blocks)
        bf16x8 kf[2][4];
        #pragma unroll
        for (int half = 0; half < 2; ++half) {
            const bf16* kp = Kb + (size_t)(s0 + half * 16 + cl) * 1024 + h * 128 + grp * 8;
            #pragma unroll
            for (int kk = 0; kk < 4; ++kk) kf[half][kk] = *(const bf16x8*)(kp + kk * 32);
        }
        // V frags issued NOW: vmcnt is in-order, so QK's wait on kf leaves
        // these in flight through softmax (~400 cyc of free latency hiding).
        bf16x8 vf[8];
        const bf16* vp = Vt + (size_t)(h * 128 + cl) * 1024 + s0 + grp * 8;
        #pragma unroll
        for (int nt = 0; nt < 8; ++nt)
            vf[nt] = *(const bf16x8*)(vp + (size_t)nt * 16 * 1024);

        const bool v0 = (s0 + cl) < 1000;
        const bool v1 = (s0 + 16 + cl) < 1000;

        #pragma unroll
        for (int m = 0; m < 2; ++m) {
            f32x4 st[2];
            #pragma unroll
            for (int half = 0; half < 2; ++half) {
                f32x4 sc = (f32x4){0.f, 0.f, 0.f, 0.f};
                #pragma unroll
                for (int kk = 0; kk < 4; ++kk)
                    sc = __builtin_amdgcn_mfma_f32_16x16x32_bf16(
                        qf[m][kk], kf[half][kk], sc, 0, 0, 0);
                st[half] = sc;
            }
            #pragma unroll
            for (int reg = 0; reg < 4; ++reg) {
                const float z0 = v0 ? st[0][reg] * sl2 : -1e30f;
                const float z1 = v1 ? st[1][reg] * sl2 : -1e30f;
                float mx = fmaxf(z0, z1);
                #pragma unroll
                for (int off = 1; off < 16; off <<= 1) mx = fmaxf(mx, __shfl_xor(mx, off));
                const float mnew = fmaxf(m_[m][reg], mx);
                const float alpha = __builtin_amdgcn_exp2f(m_[m][reg] - mnew);
                const float p0 = __builtin_amdgcn_exp2f(z0 - mnew);
                const float p1 = __builtin_amdgcn_exp2f(z1 - mnew);
                float rs = p0 + p1;
                #pragma unroll
                for (int off = 1; off < 16; off <<= 1) rs += __shfl_xor(rs, off);
                l_[m][reg] = l_[m][reg] * alpha + rs;
                m_[m][reg] = mnew;
                const int r = grp * 4 + reg;
                Pl[w][m][r * 40 + cl] = (bf16)p0;
                Pl[w][m][r * 40 + 16 + cl] = (bf16)p1;
                #pragma unroll
                for (int nt = 0; nt < 8; ++nt) o[m][nt][reg] *= alpha;
            }
        }

        // PV: wave-private P; same-wave LDS RAW ordered by lgkmcnt (no barrier).
        #pragma unroll
        for (int m = 0; m < 2; ++m) {
            const bf16x8 pa = *(const bf16x8*)(&Pl[w][m][cl * 40 + grp * 8]);
            #pragma unroll
            for (int nt = 0; nt < 8; ++nt)
                o[m][nt] = __builtin_amdgcn_mfma_f32_16x16x32_bf16(
                    pa, vf[nt], o[m][nt], 0, 0, 0);
        }
    }

    #pragma unroll
    for (int m = 0; m < 2; ++m) {
        #pragma unroll
        for (int reg = 0; reg < 4; ++reg) {
            const float inv = __builtin_amdgcn_rcpf(l_[m][reg]);
            const int row = l0 + m * 16 + grp * 4 + reg;
            #pragma unroll
            for (int nt = 0; nt < 8; ++nt) {
                const int col = h * 128 + nt * 16 + cl;
                O[(size_t)(b * 1024 + row) * 1024 + col] = (bf16)(o[m][nt][reg] * inv);
            }
        }
    }
}

// ---------------------------------------------------------------------------
extern "C" void kernel_launch(void* const* d_in, const int* in_sizes, int n_in,
                              void* d_out, int out_size, void* d_ws, size_t ws_size,
                              hipStream_t stream)
{
    const float* target = (const float*)d_in[0];  // [8192, 512]
    const float* source = (const float*)d_in[1];  // [1000, 4096]
    const float* value  = (const float*)d_in[2];  // [1000, 4096]
    const float* Wq = (const float*)d_in[3];      // [512, 1024]
    const float* bq = (const float*)d_in[4];
    const float* Wk = (const float*)d_in[5];      // [4096, 1024]
    const float* bk = (const float*)d_in[6];
    const float* Wv = (const float*)d_in[7];      // [4096, 1024]
    const float* bv = (const float*)d_in[8];
    const float* Wo = (const float*)d_in[9];      // [1024, 4096]
    const float* bo = (const float*)d_in[10];

    // d_out is fp32 [8192,4096] = 128 MB. Scratch whose lifetime ends before
    // the final GEMM lives there (61 MB). AO + WoT (read by final GEMM) -> d_ws.
    char* po = (char*)d_out;
    size_t off = 0;
    bf16* tgt_b = (bf16*)(po + off); off += (size_t)8192 * 512 * 2;   //  8 MB
    bf16* src_b = (bf16*)(po + off); off += (size_t)1024 * 4096 * 2;  //  8 MB
    bf16* val_b = (bf16*)(po + off); off += (size_t)1024 * 4096 * 2;  //  8 MB
    bf16* WqT   = (bf16*)(po + off); off += (size_t)1024 * 512 * 2;   //  1 MB
    bf16* WkT   = (bf16*)(po + off); off += (size_t)1024 * 4096 * 2;  //  8 MB
    bf16* WvT   = (bf16*)(po + off); off += (size_t)1024 * 4096 * 2;  //  8 MB
    bf16* Qb    = (bf16*)(po + off); off += (size_t)8192 * 1024 * 2;  // 16 MB
    bf16* Kb    = (bf16*)(po + off); off += (size_t)1024 * 1024 * 2;  //  2 MB
    bf16* Vt    = (bf16*)(po + off); off += (size_t)1024 * 1024 * 2;  //  2 MB = 61 MB
    char* ws = (char*)d_ws;
    bf16* AO  = (bf16*)ws;                                   // 16 MB
    bf16* WoT = (bf16*)(ws + (size_t)8192 * 1024 * 2);       //  8 MB (24 MB d_ws)

    cast_f32_bf16<<<(8192 * 512) / 2048, 256, 0, stream>>>(target, tgt_b, (size_t)8192 * 512);
    cast_f32_bf16<<<(1024 * 4096) / 2048, 256, 0, stream>>>(source, src_b, (size_t)1000 * 4096);
    cast_f32_bf16<<<(1024 * 4096) / 2048, 256, 0, stream>>>(value, val_b, (size_t)1000 * 4096);

    transpose_cast<<<dim3(32, 16), 256, 0, stream>>>(Wq, WqT, 512, 1024);
    transpose_cast<<<dim3(32, 128), 256, 0, stream>>>(Wk, WkT, 4096, 1024);
    transpose_cast<<<dim3(32, 128), 256, 0, stream>>>(Wv, WvT, 4096, 1024);
    transpose_cast<<<dim3(128, 32), 256, 0, stream>>>(Wo, WoT, 1024, 4096);

    // Q = target @ Wq + bq   [8192,1024] bf16
    gemm_bt<<<dim3(8, 64), 256, 0, stream>>>(tgt_b, WqT, bq, Qb, 8192, 1024, 512, 512, 512, 1024, 0, 0);
    // K = source @ Wk + bk   [1024,1024] bf16 (pad rows = bias; masked in flash)
    // 64-tile variant: 256 blocks instead of 64 -> fills the chip.
    gemm_bt64<<<dim3(16, 16), 256, 0, stream>>>(src_b, WkT, bk, Kb, 1024, 1024, 4096, 4096, 4096, 1024, 0, 0);
    // V^T = (value @ Wv + bv)^T  [1024 e, 1024 s] bf16
    gemm_bt64<<<dim3(16, 16), 256, 0, stream>>>(val_b, WvT, bv, Vt, 1024, 1024, 4096, 4096, 4096, 1024, 1, 0);

    // attention -> AO [8192,1024] bf16
    flash_attn<<<dim3(64, 8), 256, 0, stream>>>(Qb, Kb, Vt, AO);

    // out = AO @ Wo + bo -> d_out FP32 [8192,4096] (reads d_ws/d_in only; full overwrite)
    gemm_bt<<<dim3(32, 64), 256, 0, stream>>>(AO, WoT, bo, d_out, 8192, 4096, 1024, 1024, 1024, 4096, 0, 1);

    (void)in_sizes; (void)n_in; (void)out_size; (void)ws_size;
}